// Round 6
// baseline (154.409 us; speedup 1.0000x reference)
//
#include <hip/hip_runtime.h>

#define NN 50000
#define NE 250000
#define NT 7813        // ceil(NE/32)
#define NBLK 512

typedef __attribute__((ext_vector_type(8)))  short    s16x8;
typedef __attribute__((ext_vector_type(16))) float    f32x16;
typedef __attribute__((ext_vector_type(4)))  unsigned u32x4;
typedef __attribute__((ext_vector_type(4)))  int      i32x4;

__device__ __forceinline__ unsigned bf16r(float f) {
    unsigned u = __float_as_uint(f);
    return (u + 0x7fffu + ((u >> 16) & 1u)) >> 16;   // RNE
}
__device__ __forceinline__ short bfs(float f) {
    __bf16 b = (__bf16)f;
    return __builtin_bit_cast(short, b);
}

// ws layout (bytes):
//   w2pk  @ 0        67584   (16896 u32)
//   hist  @ 67584    200000  (50000 int)
//   rowp  @ 267584   200016  (50001 int, padded)
//   off   @ 467600   200000  (50000 int)
//   elist @ 667600   1000064 (250016 int; low 50000 reused as scan tmp)
//   blks  @ 1667664  1024    (196 int)

// ---------------------------------------------------------------------------
// K1: pack w2ext = [w2; b2] (1056x32) into bf16 B-fragment image
//     [66 steps][64 lanes][4 dwords]; zero agg (d_out); zero hist.
// ---------------------------------------------------------------------------
__global__ __launch_bounds__(256) void prep_kernel(
    const float* __restrict__ w2, const float* __restrict__ b2,
    unsigned* __restrict__ w2pk, float* __restrict__ agg,
    int* __restrict__ hist)
{
    int g = blockIdx.x * 256 + threadIdx.x;
    if (g < 16896) {
        int s = g >> 8, l = (g >> 2) & 63, q = g & 3;
        int col = l & 31;
        int kk = s * 16 + (l >> 5) * 8 + 2 * q;
        float f0 = (kk < 1024) ? w2[(kk >> 5) * 1024 + (kk & 31) * 32 + col]
                               : b2[(kk - 1024) * 32 + col];
        int k1 = kk + 1;
        float f1 = (k1 < 1024) ? w2[(k1 >> 5) * 1024 + (k1 & 31) * 32 + col]
                               : b2[(k1 - 1024) * 32 + col];
        w2pk[g] = (bf16r(f1) << 16) | bf16r(f0);
    } else {
        int c = g - 16896;
        if (c < 400000)      ((float4*)agg)[c]        = float4{0.f,0.f,0.f,0.f};
        else if (c < 412500) ((i32x4*)hist)[c-400000] = i32x4{0,0,0,0};
    }
}

// K2: histogram of dst
__global__ __launch_bounds__(256) void hist_kernel(
    const int* __restrict__ ei, int* __restrict__ hist)
{
    int e = blockIdx.x * 256 + threadIdx.x;
    if (e < NE) atomicAdd(&hist[ei[NE + e]], 1);
}

__device__ __forceinline__ int wave_incl_scan(int v, int lane) {
    #pragma unroll
    for (int o = 1; o < 64; o <<= 1) {
        int t = __shfl_up(v, o);
        if (lane >= o) v += t;
    }
    return v;
}

// K3: per-block inclusive scan of hist -> tmp; block sums -> blks
__global__ __launch_bounds__(256) void scan_a(
    const int* __restrict__ hist, int* __restrict__ tmp, int* __restrict__ blks)
{
    int g = blockIdx.x * 256 + threadIdx.x;
    int lane = threadIdx.x & 63, w = threadIdx.x >> 6;
    int v = (g < NN) ? hist[g] : 0;
    v = wave_incl_scan(v, lane);
    __shared__ int ws[4];
    if (lane == 63) ws[w] = v;
    __syncthreads();
    int add = (w > 0 ? ws[0] : 0) + (w > 1 ? ws[1] : 0) + (w > 2 ? ws[2] : 0);
    v += add;
    if (g < NN) tmp[g] = v;
    if (threadIdx.x == 255) blks[blockIdx.x] = v;
}

// K4: exclusive scan of 196 block sums (in place), single block
__global__ __launch_bounds__(256) void scan_b(int* __restrict__ blks)
{
    int i = threadIdx.x;
    int lane = i & 63, w = i >> 6;
    int v0 = (i < 196) ? blks[i] : 0;
    int v = wave_incl_scan(v0, lane);
    __shared__ int ws[4];
    if (lane == 63) ws[w] = v;
    __syncthreads();
    int add = (w > 0 ? ws[0] : 0) + (w > 1 ? ws[1] : 0) + (w > 2 ? ws[2] : 0);
    if (i < 196) blks[i] = v + add - v0;   // exclusive
}

// K5: rowp[g] = off[g] = blks[blk] + tmp[g] - hist[g]; rowp[NN] = NE
__global__ __launch_bounds__(256) void addback(
    const int* __restrict__ hist, const int* __restrict__ tmp,
    const int* __restrict__ blks, int* __restrict__ rowp, int* __restrict__ off)
{
    int g = blockIdx.x * 256 + threadIdx.x;
    if (g < NN) {
        int excl = blks[blockIdx.x] + tmp[g] - hist[g];
        rowp[g] = excl;
        off[g]  = excl;
    }
    if (g == 0) rowp[NN] = NE;
}

// K6: scatter edge ids into dst-sorted order
__global__ __launch_bounds__(256) void scatter_kernel(
    const int* __restrict__ ei, int* __restrict__ off, int* __restrict__ elist)
{
    int e = blockIdx.x * 256 + threadIdx.x;
    if (e < NE) {
        int d = ei[NE + e];
        int p = atomicAdd(&off[d], 1);
        elist[p] = e;
    }
}

// ---------------------------------------------------------------------------
// K7: edge kernel over dst-sorted edges.
//  hT = mfma(w1f, eaf); shfl h-exchange; 66+1 MFMAs; in-register same-dst
//  merge per quad (sorted edges -> runs), near-sequential atomics.
// ---------------------------------------------------------------------------
__global__ __launch_bounds__(512) void edge_kernel(
    const float* __restrict__ x, const int* __restrict__ ei,
    const float* __restrict__ ea, const float* __restrict__ w1,
    const float* __restrict__ b1, const unsigned* __restrict__ w2pk,
    const int* __restrict__ elist, float* __restrict__ agg)
{
    extern __shared__ unsigned sw2[];             // 66*256 dwords = 67584 B
    {
        const u32x4* srcp = (const u32x4*)w2pk;
        u32x4* dstp = (u32x4*)sw2;
        for (int c = threadIdx.x; c < 66 * 64; c += 512) dstp[c] = srcp[c];
    }
    __syncthreads();

    const int lane = threadIdx.x & 63;
    const int wave = threadIdx.x >> 6;
    const int er0  = lane & 31;     // tile position (A/D row); hid col (B/D)
    const int half = lane >> 5;

    // w1 B-fragment (16x32): lane l -> w1[(l>>5)*8+j][l&31]
    s16x8 w1f;
    #pragma unroll
    for (int j = 0; j < 8; j++) w1f[j] = bfs(w1[(half * 8 + j) * 32 + er0]);
    float b1r[16];
    #pragma unroll
    for (int i = 0; i < 16; i++)
        b1r[i] = b1[(i & 3) + 8 * (i >> 2) + 4 * half];

    for (int tile = blockIdx.x * 8 + wave; tile < NT; tile += NBLK * 8) {
        const int B0  = tile * 32;
        const int pos = B0 + er0;
        const int valid = pos < NE;
        const int eL = valid ? elist[pos] : 0;        // own sorted edge
        const int dL = valid ? ei[NE + eL] : -1;      // own dst (monotone)
        const int src = ei[eL];

        // x[src]: lane needs d in [half*8, half*8+8) and +16
        const float* xp = x + src * 32 + half * 8;
        float4 xa = *(const float4*)xp;
        float4 xb = *(const float4*)(xp + 4);
        float4 xc = *(const float4*)(xp + 16);
        float4 xd = *(const float4*)(xp + 20);
        float xlo[8] = {xa.x, xa.y, xa.z, xa.w, xb.x, xb.y, xb.z, xb.w};
        float xhi[8] = {xc.x, xc.y, xc.z, xc.w, xd.x, xd.y, xd.z, xd.w};

        // ea fragment: lane l -> ea[eL][(l>>5)*8+j]
        const float* epp = ea + (size_t)eL * 16 + half * 8;
        float4 e0 = *(const float4*)epp;
        float4 e1 = *(const float4*)(epp + 4);
        s16x8 eaf;
        eaf[0]=bfs(e0.x); eaf[1]=bfs(e0.y); eaf[2]=bfs(e0.z); eaf[3]=bfs(e0.w);
        eaf[4]=bfs(e1.x); eaf[5]=bfs(e1.y); eaf[6]=bfs(e1.z); eaf[7]=bfs(e1.w);

        // hT[k][e] = (ea @ w1)^T via operand swap; bias + relu
        f32x16 hc = {};
        hc = __builtin_amdgcn_mfma_f32_32x32x16_bf16(w1f, eaf, hc, 0, 0, 0);
        float X16[16];
        #pragma unroll
        for (int i = 0; i < 16; i++) X16[i] = fmaxf(hc[i] + b1r[i], 0.f);

        f32x16 acc = {};
        #pragma unroll
        for (int i = 0; i < 16; i++) {
            const float other = __shfl_xor(X16[i], 32);
            const float hA = half ? other : X16[i];
            const float hB = half ? X16[i] : other;
            const int kA = (i & 3) + 8 * (i >> 2);
            {
                s16x8 alo, ahi;
                #pragma unroll
                for (int j = 0; j < 8; j++) alo[j] = bfs(hA * xlo[j]);
                #pragma unroll
                for (int j = 0; j < 8; j++) ahi[j] = bfs(hA * xhi[j]);
                s16x8 blo = *(const s16x8*)(sw2 + (2 * kA)     * 256 + lane * 4);
                s16x8 bhi = *(const s16x8*)(sw2 + (2 * kA + 1) * 256 + lane * 4);
                acc = __builtin_amdgcn_mfma_f32_32x32x16_bf16(alo, blo, acc, 0, 0, 0);
                acc = __builtin_amdgcn_mfma_f32_32x32x16_bf16(ahi, bhi, acc, 0, 0, 0);
            }
            {
                const int kB = kA + 4;
                s16x8 alo, ahi;
                #pragma unroll
                for (int j = 0; j < 8; j++) alo[j] = bfs(hB * xlo[j]);
                #pragma unroll
                for (int j = 0; j < 8; j++) ahi[j] = bfs(hB * xhi[j]);
                s16x8 blo = *(const s16x8*)(sw2 + (2 * kB)     * 256 + lane * 4);
                s16x8 bhi = *(const s16x8*)(sw2 + (2 * kB + 1) * 256 + lane * 4);
                acc = __builtin_amdgcn_mfma_f32_32x32x16_bf16(alo, blo, acc, 0, 0, 0);
                acc = __builtin_amdgcn_mfma_f32_32x32x16_bf16(ahi, bhi, acc, 0, 0, 0);
            }
        }
        // b2 rows (h == 1): steps 64, 65
        {
            s16x8 alo, ahi;
            #pragma unroll
            for (int j = 0; j < 8; j++) alo[j] = bfs(xlo[j]);
            #pragma unroll
            for (int j = 0; j < 8; j++) ahi[j] = bfs(xhi[j]);
            s16x8 b64 = *(const s16x8*)(sw2 + 64 * 256 + lane * 4);
            s16x8 b65 = *(const s16x8*)(sw2 + 65 * 256 + lane * 4);
            acc = __builtin_amdgcn_mfma_f32_32x32x16_bf16(alo, b64, acc, 0, 0, 0);
            acc = __builtin_amdgcn_mfma_f32_32x32x16_bf16(ahi, b65, acc, 0, 0, 0);
        }

        // scatter with in-register same-dst merge. D row r -> tile position
        // p = (r&3) + 8*(r>>2) + 4*half; each quad r=4q..4q+3 covers 4
        // CONSECUTIVE sorted positions -> runs share dst.
        #pragma unroll
        for (int qq = 0; qq < 4; qq++) {
            const int base = 8 * qq + 4 * half;
            float s   = acc[4 * qq];
            int dprev = __shfl(dL, base);
            #pragma unroll
            for (int j = 1; j < 4; j++) {
                int   dj = __shfl(dL, base + j);
                float a  = acc[4 * qq + j];
                if (dj == dprev) {
                    s += a;
                } else {
                    if (dprev >= 0) atomicAdd(&agg[dprev * 32 + er0], s);
                    s = a; dprev = dj;
                }
            }
            if (dprev >= 0) atomicAdd(&agg[dprev * 32 + er0], s);
        }
    }
}

// ---------------------------------------------------------------------------
// K8: node kernel (in-place on out, which holds agg); cnt from CSR rowp
// ---------------------------------------------------------------------------
__global__ __launch_bounds__(256) void node_kernel(
    const float* __restrict__ x, const float* __restrict__ root,
    const float* __restrict__ bias_conv, const float* __restrict__ w3,
    const float* __restrict__ b3, const int* __restrict__ rowp,
    float* __restrict__ out)
{
    __shared__ float xs[8][32];
    __shared__ float ms[8][32];
    const int li = threadIdx.x >> 5, hid = threadIdx.x & 31;
    const int n = blockIdx.x * 8 + li;

    xs[li][hid] = x[n * 32 + hid];
    __syncthreads();

    float xr = 0.f;
    #pragma unroll
    for (int t = 0; t < 32; t++) xr += xs[li][t] * root[t * 32 + hid];

    int ci = rowp[n + 1] - rowp[n];
    float ic = 1.0f / (float)(ci > 0 ? ci : 1);
    float m = out[n * 32 + hid] * ic + xr + bias_conv[hid];
    ms[li][hid] = m;
    __syncthreads();

    float o = b3[hid];
    #pragma unroll
    for (int t = 0; t < 32; t++) {
        o += xs[li][t] * w3[t * 32 + hid];
        o += ms[li][t] * w3[(32 + t) * 32 + hid];
    }
    out[n * 32 + hid] = fmaxf(o, 0.f);
}

// ---------------------------------------------------------------------------
extern "C" void kernel_launch(void* const* d_in, const int* in_sizes, int n_in,
                              void* d_out, int out_size, void* d_ws, size_t ws_size,
                              hipStream_t stream) {
    const float* x    = (const float*)d_in[0];
    const int*   ei   = (const int*)  d_in[1];
    const float* ea   = (const float*)d_in[2];
    const float* w1   = (const float*)d_in[3];
    const float* b1   = (const float*)d_in[4];
    const float* w2   = (const float*)d_in[5];
    const float* b2   = (const float*)d_in[6];
    const float* root = (const float*)d_in[7];
    const float* bc   = (const float*)d_in[8];
    const float* w3   = (const float*)d_in[9];
    const float* b3   = (const float*)d_in[10];

    char* ws = (char*)d_ws;
    unsigned* w2pk  = (unsigned*)(ws + 0);
    int*      hist  = (int*)(ws + 67584);
    int*      rowp  = (int*)(ws + 267584);
    int*      off   = (int*)(ws + 467600);
    int*      elist = (int*)(ws + 667600);
    int*      blks  = (int*)(ws + 1667664);
    int*      tmp   = elist;                     // scan scratch, reused
    float*    out   = (float*)d_out;             // doubles as agg

    prep_kernel<<<1678, 256, 0, stream>>>(w2, b2, w2pk, out, hist);
    hist_kernel<<<977, 256, 0, stream>>>(ei, hist);
    scan_a<<<196, 256, 0, stream>>>(hist, tmp, blks);
    scan_b<<<1, 256, 0, stream>>>(blks);
    addback<<<196, 256, 0, stream>>>(hist, tmp, blks, rowp, off);
    scatter_kernel<<<977, 256, 0, stream>>>(ei, off, elist);

    const int lds_bytes = 66 * 1024;             // 67584
    hipFuncSetAttribute((const void*)edge_kernel,
                        hipFuncAttributeMaxDynamicSharedMemorySize, lds_bytes);
    edge_kernel<<<NBLK, 512, lds_bytes, stream>>>(x, ei, ea, w1, b1, w2pk,
                                                  elist, out);

    node_kernel<<<NN / 8, 256, 0, stream>>>(x, root, bc, w3, b3, rowp, out);
}